// Round 11
// baseline (410.102 us; speedup 1.0000x reference)
//
#include <hip/hip_runtime.h>

// 3-layer LSTM, B=4096, T=336, F=12, H=50, fp32 in/out.
// MFMA: z^T = W'(gate-permuted, gate-prescaled) @ a^T via mfma_f32_16x16x32_f16.
// R = 4*unit + gate -> each lane's 4 accumulators = 4 gates of one unit ->
// lane-local c/h update; c in registers; weights in VGPRs (loaded once).
// LAYER-SPECIALIZED WAVES: 39 cells = 13 tiles x 3 layers, each wave owns 2-3
// cells of ONE layer -> reads ONE activation plane per tick.
// Dependency-split K (round-6): L1/L2 input rows [h_self 0..49 | pad |
// h_in 64..113 | pad]; layer delay 2 ticks (L0 step t, L1 t-2, L2 t-4); the
// in-half is written a full tick before use -> PREFETCHED into registers
// during the previous tick.
// ROUND-16: X-LOAD HOIST. __syncthreads emits s_waitcnt vmcnt(0) before
// s_barrier; the stager's global load was issued ~50cy before the barrier ->
// waves 0-2 drained a fresh L2/HBM load (200-900cy) at EVERY one of 338
// barriers, and the barrier releases at max arrival (whole CU pays). The
// compiler cannot hoist the issue above the previous barrier. Fix: issue
// x(TAU+2) at the TOP of the tick body (first instruction after the
// barrier), consume it at the bottom -> the ~2000cy tick body covers the
// latency and the end-of-tick drain finds it complete. Everything else is
// byte-identical to the measured-best kernel (339us counter-dur).
// Session map (rounds 6-15): six structurally distinct schedules pin the
// block-barrier floor at ~2450cy/tick (serial chain compute->store->
// barrier->read); VALU-cut, read-position, role-split, and barrier
// amortization are all refuted; spin-sync is infra-blocked. This is the
// last causal lever; if flat, the floor is confirmed.
// 1024 threads = 16 waves (4/SIMD); cells placed 9-10 per SIMD.

#define Bsz 4096
#define Tt  336
#define BT  16
#define NTH 1024

typedef _Float16 half8 __attribute__((ext_vector_type(8)));
typedef float    floatx4 __attribute__((ext_vector_type(4)));

// act0 row: 64 halfs = 8 chunks (16B). [x 0..11 | h0_self 12..61 | pad]
// act1 row: 128 halfs = 16 chunks. [h1_self 0..49 | pad | h0_in 64..113 | pad]
// act2 row: 128 halfs = 16 chunks. [h2_self 0..49 | pad | h1_in 64..113 | pad]
// XOR-chunk swizzle: chunk c of row n stored at c ^ (n & (nchunks-1)).
struct __align__(16) SMem {
  _Float16 act0[2][BT * 64];
  _Float16 act1[2][BT * 128];
  _Float16 act2[2][BT * 128];
};  // 20480 B

__device__ __forceinline__ int offA0(int n, int L) {
  return n * 64 + ((((L >> 3) ^ n) & 7) << 3) + (L & 7);
}
__device__ __forceinline__ int offA12(int n, int L) {
  return n * 128 + ((((L >> 3) ^ n) & 15) << 3) + (L & 7);
}

// z gate-prescaled: gates i,f,o hold -log2(e)*z ; gate g holds 2*log2(e)*z.
__device__ __forceinline__ float lstm_cell(floatx4 z, float& c) {
  float ei = __builtin_amdgcn_exp2f(z[0]);
  float ef = __builtin_amdgcn_exp2f(z[1]);
  float eg = __builtin_amdgcn_exp2f(z[2]);
  float eo = __builtin_amdgcn_exp2f(z[3]);
  float ig = __builtin_amdgcn_rcpf(1.f + ei);   // sigmoid(i)
  float fg = __builtin_amdgcn_rcpf(1.f + ef);   // sigmoid(f)
  float rg = __builtin_amdgcn_rcpf(1.f + eg);
  float og = __builtin_amdgcn_rcpf(1.f + eo);   // sigmoid(o)
  float gg = 1.f - 2.f * rg;                    // tanh(g)
  c = fg * c + ig * gg;
  float ec = __builtin_amdgcn_exp2f(2.885390082f * c);
  float rc = __builtin_amdgcn_rcpf(1.f + ec);
  return og * (1.f - 2.f * rc);                 // o * tanh(c)
}

// A-fragment (8 halfs) of gate-permuted, gate-prescaled weights.
// R = 4*u + g; source row g*50+u. k<bound -> Wih; bound<=k<bound+50 -> Whh.
// (Values read past the valid K range multiply a guaranteed-zero B pad.)
__device__ __forceinline__ half8 wfrag(const float* __restrict__ Wih,
                                       const float* __restrict__ Whh,
                                       int lenih, int bound, int R, int k0) {
  half8 r = {};
  int u = R >> 2, g = R & 3;
  float sc = (g == 2) ? 2.885390082f : -1.442695041f;
  if (u < 50) {
    int row = g * 50 + u;
#pragma unroll
    for (int j = 0; j < 8; ++j) {
      int k = k0 + j;
      float v = 0.f;
      if (k < bound)           v = Wih[row * lenih + k];
      else if (k < bound + 50) v = Whh[row * 50 + (k - bound)];
      r[j] = (_Float16)(sc * v);
    }
  }
  return r;
}

#define MFMA(a, b, acc) __builtin_amdgcn_mfma_f32_16x16x32_f16((a), (b), (acc), 0, 0, 0)

__global__ __launch_bounds__(NTH, 4)
void lstm_mfma_kernel(const float* __restrict__ x,
                      const float* __restrict__ Wih0, const float* __restrict__ Whh0,
                      const float* __restrict__ bih0, const float* __restrict__ bhh0,
                      const float* __restrict__ Wih1, const float* __restrict__ Whh1,
                      const float* __restrict__ bih1, const float* __restrict__ bhh1,
                      const float* __restrict__ Wih2, const float* __restrict__ Whh2,
                      const float* __restrict__ bih2, const float* __restrict__ bhh2,
                      const float* __restrict__ Wlin, const float* __restrict__ blin,
                      float* __restrict__ out) {
  __shared__ SMem sm;
  const int tid  = threadIdx.x;
  const int blk  = blockIdx.x;
  const int lane = tid & 63;
  const int w    = tid >> 6;       // wave 0..15
  const int n    = lane & 15;      // batch col / A-row in tile
  const int q    = lane >> 4;      // quad

  // ---- zero LDS (h(-1)=0 for all layers/parities, pads=0) ----
  {
    int* zp = (int*)&sm;
    for (int i = tid; i < (int)(sizeof(SMem) / 4); i += NTH) zp[i] = 0;
  }

  // ---- wave -> (layer, cells) table; SIMD k hosts waves {k,k+4,k+8,k+12},
  //      placed so each SIMD gets 9-10 cells ----
  int Lw, nc, mm3[3] = {0, 0, 0};
  switch (w) {
    case 0:  Lw = 0; nc = 3; mm3[0] = 0;  mm3[1] = 1;  mm3[2] = 2;  break;
    case 1:  Lw = 0; nc = 2; mm3[0] = 3;  mm3[1] = 4;               break;
    case 2:  Lw = 0; nc = 3; mm3[0] = 5;  mm3[1] = 6;  mm3[2] = 7;  break;
    case 3:  Lw = 0; nc = 2; mm3[0] = 8;  mm3[1] = 9;               break;
    case 4:  Lw = 1; nc = 2; mm3[0] = 0;  mm3[1] = 1;               break;
    case 5:  Lw = 1; nc = 3; mm3[0] = 2;  mm3[1] = 3;  mm3[2] = 4;  break;
    case 6:  Lw = 1; nc = 2; mm3[0] = 5;  mm3[1] = 6;               break;
    case 7:  Lw = 1; nc = 3; mm3[0] = 7;  mm3[1] = 8;  mm3[2] = 9;  break;
    case 8:  Lw = 2; nc = 3; mm3[0] = 0;  mm3[1] = 1;  mm3[2] = 2;  break;
    case 9:  Lw = 2; nc = 2; mm3[0] = 3;  mm3[1] = 4;               break;
    case 10: Lw = 2; nc = 2; mm3[0] = 5;  mm3[1] = 6;               break;
    case 11: Lw = 2; nc = 2; mm3[0] = 7;  mm3[1] = 8;               break;
    case 12: Lw = 2; nc = 2; mm3[0] = 9;  mm3[1] = 10;              break;
    case 13: Lw = 0; nc = 3; mm3[0] = 10; mm3[1] = 11; mm3[2] = 12; break;
    case 14: Lw = 1; nc = 3; mm3[0] = 10; mm3[1] = 11; mm3[2] = 12; break;
    default: Lw = 2; nc = 2; mm3[0] = 11; mm3[1] = 12;              break;
  }
  const float* Wih = (Lw == 0) ? Wih0 : ((Lw == 1) ? Wih1 : Wih2);
  const float* Whh = (Lw == 0) ? Whh0 : ((Lw == 1) ? Whh1 : Whh2);
  const float* bih = (Lw == 0) ? bih0 : ((Lw == 1) ? bih1 : bih2);
  const float* bhh = (Lw == 0) ? bhh0 : ((Lw == 1) ? bhh1 : bhh2);

  // ---- per-cell weight fragments, biases, write offsets, c-state ----
  // af[i][0..1]: self chunks (Whh for L1/L2; packed x|h for L0)
  // af[i][2..3]: input chunks (Wih for L1/L2; unused for L0)
  half8  af[3][4];
  floatx4 bia[3];
  float  cst[3] = {0.f, 0.f, 0.f};
  int    woA[3], woB[3];
  bool   uokk[3];
#pragma unroll
  for (int i = 0; i < 3; ++i) {
    bia[i] = (floatx4){0, 0, 0, 0};
#pragma unroll
    for (int kc = 0; kc < 4; ++kc) af[i][kc] = (half8){};
    int m = mm3[i];
    int u = 4 * m + q;
    int uc = (u < 50) ? u : 49;
    uokk[i] = (i < nc) && (u < 50);
    if (Lw == 0) { woA[i] = offA0 (n, 12 + uc); woB[i] = offA12(n, 64 + uc); }
    else         { woA[i] = offA12(n, uc);      woB[i] = offA12(n, 64 + uc); }
    if (i < nc) {
      int R = 16 * m + n;
      if (Lw == 0) {
#pragma unroll
        for (int kc = 0; kc < 2; ++kc)
          af[i][kc] = wfrag(Wih, Whh, 12, 12, R, kc * 32 + q * 8);
      } else {
#pragma unroll
        for (int kc = 0; kc < 2; ++kc) {
          af[i][kc]     = wfrag(Whh, Whh, 50, 50, R, kc * 32 + q * 8);  // self
          af[i][kc + 2] = wfrag(Wih, Whh, 50, 50, R, kc * 32 + q * 8);  // input
        }
      }
      if (u < 50) {
#pragma unroll
        for (int g = 0; g < 4; ++g) {
          float sc = (g == 2) ? 2.885390082f : -1.442695041f;
          bia[i][g] = sc * (bih[g * 50 + u] + bhh[g * 50 + u]);
        }
      }
    }
  }

  // ---- lane-constant LDS read offsets (halfs) ----
  const int ro0[2] = { offA0(n, q * 8), offA0(n, 32 + q * 8) };
  const int ro1[4] = { offA12(n, q * 8),      offA12(n, 32 + q * 8),    // self
                       offA12(n, 64 + q * 8), offA12(n, 96 + q * 8) };  // input

  // ---- input-fragment prefetch double-buffer (registers) ----
  half8 bpf[2][2] = {};

  // ---- x stager: tid<192 = waves 0..2 (L0 waves), 16 rows x 12 feats ----
  const int sr = (tid < 192) ? tid / 12 : 0;
  const int sf = (tid < 192) ? tid - sr * 12 : 0;
  const int sxo = offA0(sr, sf);
  const float* xp = x + ((size_t)(blk * BT + sr) * Tt) * 12 + sf;
  float xnext = 0.f;

  __syncthreads();   // zero-fill visible
  if (tid < 192) {
    sm.act0[0][sxo] = (_Float16)xp[0];   // x(0) into parity-0 buffer
    xnext = xp[12];                      // x(1)
  }
  __syncthreads();

  // Tick TAU (parity p = TAU&1): read planes [p], write planes [1-p].
  // L0 computes step TAU (TAU<=335), L1 step TAU-2 (2<=TAU<=337),
  // L2 step TAU-4 (4<=TAU<=339). L1 prefetch active 1<=TAU<=336,
  // L2 prefetch active 3<=TAU<=338. CHK=1 -> literal-TAU folds (fill/drain).
  // ROUND-16: x(TAU+2) load ISSUED FIRST (post-barrier), consumed at the
  // bottom -> the tick body hides its latency before the barrier's vmcnt(0).
#define TICK(p, TAU, CHK)                                                  \
  {                                                                        \
    float xload = 0.f;                                                     \
    if (tid < 192 && (TAU) + 2 < Tt) xload = xp[((TAU) + 2) * 12];         \
    if (Lw == 0) {                                                         \
      if (!(CHK) || (TAU) <= 335) {                                        \
        half8 b0 = *(const half8*)&sm.act0[p][ro0[0]];                     \
        half8 b1 = *(const half8*)&sm.act0[p][ro0[1]];                     \
        for (int i = 0; i < 3; ++i) if (i < nc) {                          \
          floatx4 z = bia[i];                                              \
          z = MFMA(af[i][0], b0, z);                                       \
          z = MFMA(af[i][1], b1, z);                                       \
          float h = lstm_cell(z, cst[i]);                                  \
          _Float16 hh = (_Float16)h;                                       \
          if (uokk[i]) { sm.act0[1 - (p)][woA[i]] = hh;                    \
                         sm.act1[1 - (p)][woB[i]] = hh; }                  \
        }                                                                  \
      }                                                                    \
    } else if (Lw == 1) {                                                  \
      half8 b0 = {}, b1 = {};                                              \
      if (!(CHK) || ((TAU) >= 2 && (TAU) <= 337)) {                        \
        b0 = *(const half8*)&sm.act1[p][ro1[0]];                           \
        b1 = *(const half8*)&sm.act1[p][ro1[1]];                           \
      }                                                                    \
      if (!(CHK) || ((TAU) >= 1 && (TAU) <= 336)) {                        \
        bpf[1 - (p)][0] = *(const half8*)&sm.act1[p][ro1[2]];              \
        bpf[1 - (p)][1] = *(const half8*)&sm.act1[p][ro1[3]];              \
      }                                                                    \
      if (!(CHK) || ((TAU) >= 2 && (TAU) <= 337)) {                        \
        for (int i = 0; i < 3; ++i) if (i < nc) {                          \
          floatx4 z = bia[i];                                              \
          z = MFMA(af[i][2], bpf[p][0], z);                                \
          z = MFMA(af[i][3], bpf[p][1], z);                                \
          z = MFMA(af[i][0], b0, z);                                       \
          z = MFMA(af[i][1], b1, z);                                       \
          float h = lstm_cell(z, cst[i]);                                  \
          _Float16 hh = (_Float16)h;                                       \
          if (uokk[i]) { sm.act1[1 - (p)][woA[i]] = hh;                    \
                         sm.act2[1 - (p)][woB[i]] = hh; }                  \
        }                                                                  \
      }                                                                    \
    } else {                                                               \
      half8 b0 = {}, b1 = {};                                              \
      if (!(CHK) || ((TAU) >= 4 && (TAU) <= 339)) {                        \
        b0 = *(const half8*)&sm.act2[p][ro1[0]];                           \
        b1 = *(const half8*)&sm.act2[p][ro1[1]];                           \
      }                                                                    \
      if (!(CHK) || ((TAU) >= 3 && (TAU) <= 338)) {                        \
        bpf[1 - (p)][0] = *(const half8*)&sm.act2[p][ro1[2]];              \
        bpf[1 - (p)][1] = *(const half8*)&sm.act2[p][ro1[3]];              \
      }                                                                    \
      if (!(CHK) || ((TAU) >= 4 && (TAU) <= 339)) {                        \
        for (int i = 0; i < 3; ++i) if (i < nc) {                          \
          floatx4 z = bia[i];                                              \
          z = MFMA(af[i][2], bpf[p][0], z);                                \
          z = MFMA(af[i][3], bpf[p][1], z);                                \
          z = MFMA(af[i][0], b0, z);                                       \
          z = MFMA(af[i][1], b1, z);                                       \
          float h = lstm_cell(z, cst[i]);                                  \
          if (uokk[i]) sm.act2[1 - (p)][woA[i]] = (_Float16)h;             \
        }                                                                  \
      }                                                                    \
    }                                                                      \
    if (tid < 192) {                                                       \
      if ((TAU) + 1 < Tt) sm.act0[1 - (p)][sxo] = (_Float16)xnext;         \
      xnext = xload;                                                       \
    }                                                                      \
    __syncthreads();                                                       \
  }

  // fill (literal TAU -> activity folds at compile time)
  TICK(0, 0, 1)
  TICK(1, 1, 1)
  TICK(0, 2, 1)
  TICK(1, 3, 1)
  // steady: ticks 4..335 (332 ticks, unroll-2 for literal parity)
#pragma unroll 1
  for (int t = 4; t < Tt; t += 2) {
    TICK(0, t, 0)
    TICK(1, t + 1, 0)
  }
  // drain
  TICK(0, 336, 1)
  TICK(1, 337, 1)
  TICK(0, 338, 1)
  TICK(1, 339, 1)
#undef TICK

  // ---- epilogue: out[r] = b_lin + h2(335) . W_lin ----
  // L2 step 335 ran at tick 339 (p=1) -> wrote act2[0] self-half (halfs 0..49)
  if (tid < BT) {
    float s = blin[0];
    for (int uu = 0; uu < 50; ++uu)
      s += Wlin[uu] * (float)sm.act2[0][offA12(tid, uu)];
    out[blk * BT + tid] = s;
  }
}

extern "C" void kernel_launch(void* const* d_in, const int* in_sizes, int n_in,
                              void* d_out, int out_size, void* d_ws, size_t ws_size,
                              hipStream_t stream) {
  const float* x    = (const float*)d_in[0];
  const float* Wih0 = (const float*)d_in[1];
  const float* Whh0 = (const float*)d_in[2];
  const float* bih0 = (const float*)d_in[3];
  const float* bhh0 = (const float*)d_in[4];
  const float* Wih1 = (const float*)d_in[5];
  const float* Whh1 = (const float*)d_in[6];
  const float* bih1 = (const float*)d_in[7];
  const float* bhh1 = (const float*)d_in[8];
  const float* Wih2 = (const float*)d_in[9];
  const float* Whh2 = (const float*)d_in[10];
  const float* bih2 = (const float*)d_in[11];
  const float* bhh2 = (const float*)d_in[12];
  const float* Wlin = (const float*)d_in[13];
  const float* blin = (const float*)d_in[14];
  float* outp = (float*)d_out;

  dim3 grid(Bsz / BT);   // 256 blocks, 1 per CU
  dim3 block(NTH);       // 16 waves -> 4 per SIMD
  lstm_mfma_kernel<<<grid, block, 0, stream>>>(
      x, Wih0, Whh0, bih0, bhh0, Wih1, Whh1, bih1, bhh1,
      Wih2, Whh2, bih2, bhh2, Wlin, blin, outp);
}

// Round 12
// 394.511 us; speedup vs baseline: 1.0395x; 1.0395x over previous
//
#include <hip/hip_runtime.h>

// 3-layer LSTM, B=4096, T=336, F=12, H=50, fp32 in/out.
// MFMA: z^T = W'(gate-permuted, gate-prescaled) @ a^T via mfma_f32_16x16x32_f16.
// R = 4*unit + gate -> each lane's 4 accumulators = 4 gates of one unit ->
// lane-local c/h update; c in registers; weights in VGPRs (loaded once).
// LAYER-SPECIALIZED WAVES: 39 cells = 13 tiles x 3 layers, each wave owns 2-3
// cells of ONE layer -> reads ONE activation plane per tick.
// Dependency-split K: L1/L2 input rows [h_self 0..49 | pad | h_in 64..113 |
// pad]; layer delay 2 ticks (L0 step t, L1 t-2, L2 t-4); the in-half is
// written a full tick before use -> PREFETCHED into registers during the
// previous tick.
// FINAL (round-17): measured-best kernel, locked. Session map (R6-R16):
// seven structurally distinct schedules — homogeneous x3 (345-348us),
// this one (338.7us, best), heterogeneous roles (348us), whole-layer
// super-ticks (613us), x-load hoist (355us) — pin the block-barrier
// structural floor at ~2450cy/tick: the serial chain compute -> store ->
// barrier -> read forced by the distance-1 cross-wave self-recurrence.
// VALU-cut (R3: busy 63->57%, flat), read-placement (R8 full dbuf, flat),
// role-split (R8', flat), barrier amortization (R9: exposed latency, worse),
// and x-hoist (R11: worse) are all refuted. Neither pipe is near its
// roofline (VALU 63%, MFMA 24%): the bound is synchronization. The only
// chain-breaking mechanism (de-phased producer/consumer spin sync) killed
// the container twice and is infrastructure-blocked.
// 1024 threads = 16 waves (4/SIMD); cells placed 9-10 per SIMD.

#define Bsz 4096
#define Tt  336
#define BT  16
#define NTH 1024

typedef _Float16 half8 __attribute__((ext_vector_type(8)));
typedef float    floatx4 __attribute__((ext_vector_type(4)));

// act0 row: 64 halfs = 8 chunks (16B). [x 0..11 | h0_self 12..61 | pad]
// act1 row: 128 halfs = 16 chunks. [h1_self 0..49 | pad | h0_in 64..113 | pad]
// act2 row: 128 halfs = 16 chunks. [h2_self 0..49 | pad | h1_in 64..113 | pad]
// XOR-chunk swizzle: chunk c of row n stored at c ^ (n & (nchunks-1)).
struct __align__(16) SMem {
  _Float16 act0[2][BT * 64];
  _Float16 act1[2][BT * 128];
  _Float16 act2[2][BT * 128];
};  // 20480 B

__device__ __forceinline__ int offA0(int n, int L) {
  return n * 64 + ((((L >> 3) ^ n) & 7) << 3) + (L & 7);
}
__device__ __forceinline__ int offA12(int n, int L) {
  return n * 128 + ((((L >> 3) ^ n) & 15) << 3) + (L & 7);
}

// z gate-prescaled: gates i,f,o hold -log2(e)*z ; gate g holds 2*log2(e)*z.
__device__ __forceinline__ float lstm_cell(floatx4 z, float& c) {
  float ei = __builtin_amdgcn_exp2f(z[0]);
  float ef = __builtin_amdgcn_exp2f(z[1]);
  float eg = __builtin_amdgcn_exp2f(z[2]);
  float eo = __builtin_amdgcn_exp2f(z[3]);
  float ig = __builtin_amdgcn_rcpf(1.f + ei);   // sigmoid(i)
  float fg = __builtin_amdgcn_rcpf(1.f + ef);   // sigmoid(f)
  float rg = __builtin_amdgcn_rcpf(1.f + eg);
  float og = __builtin_amdgcn_rcpf(1.f + eo);   // sigmoid(o)
  float gg = 1.f - 2.f * rg;                    // tanh(g)
  c = fg * c + ig * gg;
  float ec = __builtin_amdgcn_exp2f(2.885390082f * c);
  float rc = __builtin_amdgcn_rcpf(1.f + ec);
  return og * (1.f - 2.f * rc);                 // o * tanh(c)
}

// A-fragment (8 halfs) of gate-permuted, gate-prescaled weights.
// R = 4*u + g; source row g*50+u. k<bound -> Wih; bound<=k<bound+50 -> Whh.
// (Values read past the valid K range multiply a guaranteed-zero B pad.)
__device__ __forceinline__ half8 wfrag(const float* __restrict__ Wih,
                                       const float* __restrict__ Whh,
                                       int lenih, int bound, int R, int k0) {
  half8 r = {};
  int u = R >> 2, g = R & 3;
  float sc = (g == 2) ? 2.885390082f : -1.442695041f;
  if (u < 50) {
    int row = g * 50 + u;
#pragma unroll
    for (int j = 0; j < 8; ++j) {
      int k = k0 + j;
      float v = 0.f;
      if (k < bound)           v = Wih[row * lenih + k];
      else if (k < bound + 50) v = Whh[row * 50 + (k - bound)];
      r[j] = (_Float16)(sc * v);
    }
  }
  return r;
}

#define MFMA(a, b, acc) __builtin_amdgcn_mfma_f32_16x16x32_f16((a), (b), (acc), 0, 0, 0)

__global__ __launch_bounds__(NTH, 4)
void lstm_mfma_kernel(const float* __restrict__ x,
                      const float* __restrict__ Wih0, const float* __restrict__ Whh0,
                      const float* __restrict__ bih0, const float* __restrict__ bhh0,
                      const float* __restrict__ Wih1, const float* __restrict__ Whh1,
                      const float* __restrict__ bih1, const float* __restrict__ bhh1,
                      const float* __restrict__ Wih2, const float* __restrict__ Whh2,
                      const float* __restrict__ bih2, const float* __restrict__ bhh2,
                      const float* __restrict__ Wlin, const float* __restrict__ blin,
                      float* __restrict__ out) {
  __shared__ SMem sm;
  const int tid  = threadIdx.x;
  const int blk  = blockIdx.x;
  const int lane = tid & 63;
  const int w    = tid >> 6;       // wave 0..15
  const int n    = lane & 15;      // batch col / A-row in tile
  const int q    = lane >> 4;      // quad

  // ---- zero LDS (h(-1)=0 for all layers/parities, pads=0) ----
  {
    int* zp = (int*)&sm;
    for (int i = tid; i < (int)(sizeof(SMem) / 4); i += NTH) zp[i] = 0;
  }

  // ---- wave -> (layer, cells) table; SIMD k hosts waves {k,k+4,k+8,k+12},
  //      placed so each SIMD gets 9-10 cells ----
  int Lw, nc, mm3[3] = {0, 0, 0};
  switch (w) {
    case 0:  Lw = 0; nc = 3; mm3[0] = 0;  mm3[1] = 1;  mm3[2] = 2;  break;
    case 1:  Lw = 0; nc = 2; mm3[0] = 3;  mm3[1] = 4;               break;
    case 2:  Lw = 0; nc = 3; mm3[0] = 5;  mm3[1] = 6;  mm3[2] = 7;  break;
    case 3:  Lw = 0; nc = 2; mm3[0] = 8;  mm3[1] = 9;               break;
    case 4:  Lw = 1; nc = 2; mm3[0] = 0;  mm3[1] = 1;               break;
    case 5:  Lw = 1; nc = 3; mm3[0] = 2;  mm3[1] = 3;  mm3[2] = 4;  break;
    case 6:  Lw = 1; nc = 2; mm3[0] = 5;  mm3[1] = 6;               break;
    case 7:  Lw = 1; nc = 3; mm3[0] = 7;  mm3[1] = 8;  mm3[2] = 9;  break;
    case 8:  Lw = 2; nc = 3; mm3[0] = 0;  mm3[1] = 1;  mm3[2] = 2;  break;
    case 9:  Lw = 2; nc = 2; mm3[0] = 3;  mm3[1] = 4;               break;
    case 10: Lw = 2; nc = 2; mm3[0] = 5;  mm3[1] = 6;               break;
    case 11: Lw = 2; nc = 2; mm3[0] = 7;  mm3[1] = 8;               break;
    case 12: Lw = 2; nc = 2; mm3[0] = 9;  mm3[1] = 10;              break;
    case 13: Lw = 0; nc = 3; mm3[0] = 10; mm3[1] = 11; mm3[2] = 12; break;
    case 14: Lw = 1; nc = 3; mm3[0] = 10; mm3[1] = 11; mm3[2] = 12; break;
    default: Lw = 2; nc = 2; mm3[0] = 11; mm3[1] = 12;              break;
  }
  const float* Wih = (Lw == 0) ? Wih0 : ((Lw == 1) ? Wih1 : Wih2);
  const float* Whh = (Lw == 0) ? Whh0 : ((Lw == 1) ? Whh1 : Whh2);
  const float* bih = (Lw == 0) ? bih0 : ((Lw == 1) ? bih1 : bih2);
  const float* bhh = (Lw == 0) ? bhh0 : ((Lw == 1) ? bhh1 : bhh2);

  // ---- per-cell weight fragments, biases, write offsets, c-state ----
  // af[i][0..1]: self chunks (Whh for L1/L2; packed x|h for L0)
  // af[i][2..3]: input chunks (Wih for L1/L2; unused for L0)
  half8  af[3][4];
  floatx4 bia[3];
  float  cst[3] = {0.f, 0.f, 0.f};
  int    woA[3], woB[3];
  bool   uokk[3];
#pragma unroll
  for (int i = 0; i < 3; ++i) {
    bia[i] = (floatx4){0, 0, 0, 0};
#pragma unroll
    for (int kc = 0; kc < 4; ++kc) af[i][kc] = (half8){};
    int m = mm3[i];
    int u = 4 * m + q;
    int uc = (u < 50) ? u : 49;
    uokk[i] = (i < nc) && (u < 50);
    if (Lw == 0) { woA[i] = offA0 (n, 12 + uc); woB[i] = offA12(n, 64 + uc); }
    else         { woA[i] = offA12(n, uc);      woB[i] = offA12(n, 64 + uc); }
    if (i < nc) {
      int R = 16 * m + n;
      if (Lw == 0) {
#pragma unroll
        for (int kc = 0; kc < 2; ++kc)
          af[i][kc] = wfrag(Wih, Whh, 12, 12, R, kc * 32 + q * 8);
      } else {
#pragma unroll
        for (int kc = 0; kc < 2; ++kc) {
          af[i][kc]     = wfrag(Whh, Whh, 50, 50, R, kc * 32 + q * 8);  // self
          af[i][kc + 2] = wfrag(Wih, Whh, 50, 50, R, kc * 32 + q * 8);  // input
        }
      }
      if (u < 50) {
#pragma unroll
        for (int g = 0; g < 4; ++g) {
          float sc = (g == 2) ? 2.885390082f : -1.442695041f;
          bia[i][g] = sc * (bih[g * 50 + u] + bhh[g * 50 + u]);
        }
      }
    }
  }

  // ---- lane-constant LDS read offsets (halfs) ----
  const int ro0[2] = { offA0(n, q * 8), offA0(n, 32 + q * 8) };
  const int ro1[4] = { offA12(n, q * 8),      offA12(n, 32 + q * 8),    // self
                       offA12(n, 64 + q * 8), offA12(n, 96 + q * 8) };  // input

  // ---- input-fragment prefetch double-buffer (registers) ----
  half8 bpf[2][2] = {};

  // ---- x stager: tid<192 = waves 0..2 (L0 waves), 16 rows x 12 feats ----
  const int sr = (tid < 192) ? tid / 12 : 0;
  const int sf = (tid < 192) ? tid - sr * 12 : 0;
  const int sxo = offA0(sr, sf);
  const float* xp = x + ((size_t)(blk * BT + sr) * Tt) * 12 + sf;
  float xnext = 0.f;

  __syncthreads();   // zero-fill visible
  if (tid < 192) {
    sm.act0[0][sxo] = (_Float16)xp[0];   // x(0) into parity-0 buffer
    xnext = xp[12];                      // x(1)
  }
  __syncthreads();

  // Tick TAU (parity p = TAU&1): read planes [p], write planes [1-p].
  // L0 computes step TAU (TAU<=335), L1 step TAU-2 (2<=TAU<=337),
  // L2 step TAU-4 (4<=TAU<=339). L1 prefetch active 1<=TAU<=336,
  // L2 prefetch active 3<=TAU<=338. CHK=1 -> literal-TAU folds (fill/drain).
#define TICK(p, TAU, CHK)                                                  \
  {                                                                        \
    if (Lw == 0) {                                                         \
      if (!(CHK) || (TAU) <= 335) {                                        \
        half8 b0 = *(const half8*)&sm.act0[p][ro0[0]];                     \
        half8 b1 = *(const half8*)&sm.act0[p][ro0[1]];                     \
        for (int i = 0; i < 3; ++i) if (i < nc) {                          \
          floatx4 z = bia[i];                                              \
          z = MFMA(af[i][0], b0, z);                                       \
          z = MFMA(af[i][1], b1, z);                                       \
          float h = lstm_cell(z, cst[i]);                                  \
          _Float16 hh = (_Float16)h;                                       \
          if (uokk[i]) { sm.act0[1 - (p)][woA[i]] = hh;                    \
                         sm.act1[1 - (p)][woB[i]] = hh; }                  \
        }                                                                  \
      }                                                                    \
    } else if (Lw == 1) {                                                  \
      half8 b0 = {}, b1 = {};                                              \
      if (!(CHK) || ((TAU) >= 2 && (TAU) <= 337)) {                        \
        b0 = *(const half8*)&sm.act1[p][ro1[0]];                           \
        b1 = *(const half8*)&sm.act1[p][ro1[1]];                           \
      }                                                                    \
      if (!(CHK) || ((TAU) >= 1 && (TAU) <= 336)) {                        \
        bpf[1 - (p)][0] = *(const half8*)&sm.act1[p][ro1[2]];              \
        bpf[1 - (p)][1] = *(const half8*)&sm.act1[p][ro1[3]];              \
      }                                                                    \
      if (!(CHK) || ((TAU) >= 2 && (TAU) <= 337)) {                        \
        for (int i = 0; i < 3; ++i) if (i < nc) {                          \
          floatx4 z = bia[i];                                              \
          z = MFMA(af[i][2], bpf[p][0], z);                                \
          z = MFMA(af[i][3], bpf[p][1], z);                                \
          z = MFMA(af[i][0], b0, z);                                       \
          z = MFMA(af[i][1], b1, z);                                       \
          float h = lstm_cell(z, cst[i]);                                  \
          _Float16 hh = (_Float16)h;                                       \
          if (uokk[i]) { sm.act1[1 - (p)][woA[i]] = hh;                    \
                         sm.act2[1 - (p)][woB[i]] = hh; }                  \
        }                                                                  \
      }                                                                    \
    } else {                                                               \
      half8 b0 = {}, b1 = {};                                              \
      if (!(CHK) || ((TAU) >= 4 && (TAU) <= 339)) {                        \
        b0 = *(const half8*)&sm.act2[p][ro1[0]];                           \
        b1 = *(const half8*)&sm.act2[p][ro1[1]];                           \
      }                                                                    \
      if (!(CHK) || ((TAU) >= 3 && (TAU) <= 338)) {                        \
        bpf[1 - (p)][0] = *(const half8*)&sm.act2[p][ro1[2]];              \
        bpf[1 - (p)][1] = *(const half8*)&sm.act2[p][ro1[3]];              \
      }                                                                    \
      if (!(CHK) || ((TAU) >= 4 && (TAU) <= 339)) {                        \
        for (int i = 0; i < 3; ++i) if (i < nc) {                          \
          floatx4 z = bia[i];                                              \
          z = MFMA(af[i][2], bpf[p][0], z);                                \
          z = MFMA(af[i][3], bpf[p][1], z);                                \
          z = MFMA(af[i][0], b0, z);                                       \
          z = MFMA(af[i][1], b1, z);                                       \
          float h = lstm_cell(z, cst[i]);                                  \
          if (uokk[i]) sm.act2[1 - (p)][woA[i]] = (_Float16)h;             \
        }                                                                  \
      }                                                                    \
    }                                                                      \
    if (tid < 192) {                                                       \
      if ((TAU) + 1 < Tt) sm.act0[1 - (p)][sxo] = (_Float16)xnext;         \
      xnext = ((TAU) + 2 < Tt) ? xp[((TAU) + 2) * 12] : 0.f;               \
    }                                                                      \
    __syncthreads();                                                       \
  }

  // fill (literal TAU -> activity folds at compile time)
  TICK(0, 0, 1)
  TICK(1, 1, 1)
  TICK(0, 2, 1)
  TICK(1, 3, 1)
  // steady: ticks 4..335 (332 ticks, unroll-2 for literal parity)
#pragma unroll 1
  for (int t = 4; t < Tt; t += 2) {
    TICK(0, t, 0)
    TICK(1, t + 1, 0)
  }
  // drain
  TICK(0, 336, 1)
  TICK(1, 337, 1)
  TICK(0, 338, 1)
  TICK(1, 339, 1)
#undef TICK

  // ---- epilogue: out[r] = b_lin + h2(335) . W_lin ----
  // L2 step 335 ran at tick 339 (p=1) -> wrote act2[0] self-half (halfs 0..49)
  if (tid < BT) {
    float s = blin[0];
    for (int uu = 0; uu < 50; ++uu)
      s += Wlin[uu] * (float)sm.act2[0][offA12(tid, uu)];
    out[blk * BT + tid] = s;
  }
}

extern "C" void kernel_launch(void* const* d_in, const int* in_sizes, int n_in,
                              void* d_out, int out_size, void* d_ws, size_t ws_size,
                              hipStream_t stream) {
  const float* x    = (const float*)d_in[0];
  const float* Wih0 = (const float*)d_in[1];
  const float* Whh0 = (const float*)d_in[2];
  const float* bih0 = (const float*)d_in[3];
  const float* bhh0 = (const float*)d_in[4];
  const float* Wih1 = (const float*)d_in[5];
  const float* Whh1 = (const float*)d_in[6];
  const float* bih1 = (const float*)d_in[7];
  const float* bhh1 = (const float*)d_in[8];
  const float* Wih2 = (const float*)d_in[9];
  const float* Whh2 = (const float*)d_in[10];
  const float* bih2 = (const float*)d_in[11];
  const float* bhh2 = (const float*)d_in[12];
  const float* Wlin = (const float*)d_in[13];
  const float* blin = (const float*)d_in[14];
  float* outp = (float*)d_out;

  dim3 grid(Bsz / BT);   // 256 blocks, 1 per CU
  dim3 block(NTH);       // 16 waves -> 4 per SIMD
  lstm_mfma_kernel<<<grid, block, 0, stream>>>(
      x, Wih0, Whh0, bih0, bhh0, Wih1, Whh1, bih1, bhh1,
      Wih2, Whh2, bih2, bhh2, Wlin, blin, outp);
}